// Round 11
// baseline (221.664 us; speedup 1.0000x reference)
//
#include <hip/hip_runtime.h>
#include <math.h>

#define NUM 2048
#define CDIM 256
#define NUM_LAYER 4

typedef short bf16x8 __attribute__((ext_vector_type(8)));
typedef unsigned short u16x8 __attribute__((ext_vector_type(8)));
typedef float f32x4 __attribute__((ext_vector_type(4)));

static __device__ __forceinline__ unsigned short f2bf(float f) {
  unsigned u = __float_as_uint(f);
  unsigned r = 0x7FFFu + ((u >> 16) & 1u);
  return (unsigned short)((u + r) >> 16);
}
static __device__ __forceinline__ float bf2f(unsigned short h) {
  return __uint_as_float(((unsigned)h) << 16);
}

// ---------------- projection + bf16 3-way split (x = hi + mid + lo, residuals
// exact). Epilogue transposes through LDS so component stores are coalesced.
__global__ __launch_bounds__(256) void proj_kernel(
    const float* __restrict__ Wq, const float* __restrict__ bq,
    const float* __restrict__ Wk, const float* __restrict__ bk,
    const float* __restrict__ vf, const float* __restrict__ ef,
    unsigned short* __restrict__ Qhi, unsigned short* __restrict__ Qmd,
    unsigned short* __restrict__ Qlo, unsigned short* __restrict__ Khi,
    unsigned short* __restrict__ Kmd, unsigned short* __restrict__ Klo)
{
  const int z = blockIdx.z;
  const int b = z >> 1, mm2 = z & 1;
  const float* __restrict__ Wmat = mm2 ? Wk : Wq;
  const float* __restrict__ bias = mm2 ? bk : bq;
  const float* __restrict__ x = (mm2 ? ef : vf) + (size_t)b * CDIM * NUM;
  unsigned short* __restrict__ ohi = mm2 ? Khi : Qhi;
  unsigned short* __restrict__ omd = mm2 ? Kmd : Qmd;
  unsigned short* __restrict__ olo = mm2 ? Klo : Qlo;

  const int n0 = blockIdx.x * 64;
  const int o0 = blockIdx.y * 64;
  __shared__ float Xs[32][65];
  __shared__ float Ws[64][33];
  __shared__ float T[64][69];
  const int t = threadIdx.x;
  const int tx = t & 15, ty = t >> 4;

  float acc[4][4];
  #pragma unroll
  for (int a = 0; a < 4; a++)
    #pragma unroll
    for (int c = 0; c < 4; c++) acc[a][c] = 0.0f;

  for (int cc = 0; cc < CDIM; cc += 32) {
    #pragma unroll
    for (int e = 0; e < 2; e++) {
      int f = t * 2 + e;
      int row = f >> 4, c4 = f & 15;
      const float4 v = *(const float4*)(&x[(size_t)(cc + row) * NUM + n0 + c4 * 4]);
      Xs[row][c4*4+0] = v.x; Xs[row][c4*4+1] = v.y;
      Xs[row][c4*4+2] = v.z; Xs[row][c4*4+3] = v.w;
    }
    #pragma unroll
    for (int e = 0; e < 2; e++) {
      int f = t * 2 + e;
      int row = f >> 3, c4 = f & 7;
      const float4 v = *(const float4*)(&Wmat[(size_t)(o0 + row) * CDIM + cc + c4 * 4]);
      Ws[row][c4*4+0] = v.x; Ws[row][c4*4+1] = v.y;
      Ws[row][c4*4+2] = v.z; Ws[row][c4*4+3] = v.w;
    }
    __syncthreads();
    #pragma unroll
    for (int kk = 0; kk < 32; kk++) {
      float xv[4], wv[4];
      #pragma unroll
      for (int j = 0; j < 4; j++) xv[j] = Xs[kk][tx*4+j];
      #pragma unroll
      for (int j = 0; j < 4; j++) wv[j] = Ws[ty*4+j][kk];
      #pragma unroll
      for (int oi = 0; oi < 4; oi++)
        #pragma unroll
        for (int ni = 0; ni < 4; ni++)
          acc[oi][ni] = fmaf(wv[oi], xv[ni], acc[oi][ni]);
    }
    __syncthreads();
  }
  float bb[4];
  #pragma unroll
  for (int oi = 0; oi < 4; oi++) bb[oi] = bias[o0 + ty*4 + oi];
  #pragma unroll
  for (int ni = 0; ni < 4; ni++)
    #pragma unroll
    for (int oi = 0; oi < 4; oi++)
      T[tx*4+ni][ty*4+oi] = acc[oi][ni] + bb[oi];
  __syncthreads();
  const int n_l = t >> 2;
  const int oc  = (t & 3) * 16;
  float xv[16];
  #pragma unroll
  for (int j = 0; j < 16; j++) xv[j] = T[n_l][oc + j];
  unsigned short hi[16], md[16], lo[16];
  #pragma unroll
  for (int j = 0; j < 16; j++) {
    unsigned short h = f2bf(xv[j]);
    float r1 = xv[j] - bf2f(h);
    unsigned short mdj = f2bf(r1);
    float r2 = r1 - bf2f(mdj);
    hi[j] = h; md[j] = mdj; lo[j] = f2bf(r2);
  }
  const size_t gb = ((size_t)b * NUM + n0 + n_l) * CDIM + o0 + oc;
  *(u16x8*)&ohi[gb]   = *(u16x8*)&hi[0];
  *(u16x8*)&ohi[gb+8] = *(u16x8*)&hi[8];
  *(u16x8*)&omd[gb]   = *(u16x8*)&md[0];
  *(u16x8*)&omd[gb+8] = *(u16x8*)&md[8];
  *(u16x8*)&olo[gb]   = *(u16x8*)&lo[0];
  *(u16x8*)&olo[gb+8] = *(u16x8*)&lo[8];
}

// ---------------- score via MFMA (bf16 3-way split, 6 products = fp32-equiv).
// R9 structure (4 waves, 128x128, stride 36 — measured 63 us) with ONE change:
// the lo component is NOT LDS-staged; each wave prefetches its own Qlo/Klo
// fragments direct from global (L2-resident) one head ahead. LDS 55.3->36.9 KB
// -> 3-4 blocks/CU. Values + FMA order bit-identical to R9.
__global__ __launch_bounds__(256) void score_kernel(
    const unsigned short* __restrict__ Qhi, const unsigned short* __restrict__ Qmd,
    const unsigned short* __restrict__ Qlo, const unsigned short* __restrict__ Khi,
    const unsigned short* __restrict__ Kmd, const unsigned short* __restrict__ Klo,
    const float* __restrict__ H0, float* __restrict__ score)
{
  const int b = blockIdx.z;
  const int i0 = blockIdx.x * 128;
  const int o0 = blockIdx.y * 128;
  const int t = threadIdx.x, lane = t & 63, wave = t >> 6;
  const int m = lane & 15, quad = lane >> 4;
  const int obl = (wave >> 1) * 64;   // local o base of this wave
  const int ibl = (wave & 1) * 64;    // local i base

  __shared__ unsigned short qsh[2][128][36];
  __shared__ unsigned short ksh[2][128][36];

  const int srow = t >> 2;            // 0..63 (plus +64 on second pass)
  const int schk = (t & 3) * 8;       // short offset within 32-col row

  f32x4 ssum[4][4];
  #pragma unroll
  for (int a = 0; a < 4; a++)
    #pragma unroll
    for (int c = 0; c < 4; c++) ssum[a][c] = (f32x4){0.f, 0.f, 0.f, 0.f};

  const float SC = -1.4426950408889634f * 0.17677669529663687f;  // -log2(e)/sqrt(32)

  u16x8 pq[2][2], pk[2][2];
  bf16x8 aLo[4], bLo[4];
  // prologue: head 0 — hi/md to staging regs, per-wave lo fragments direct
  #pragma unroll
  for (int e = 0; e < 2; e++) {
    const size_t go = ((size_t)b * NUM + o0 + srow + 64*e) * CDIM + schk;
    const size_t gi = ((size_t)b * NUM + i0 + srow + 64*e) * CDIM + schk;
    pq[0][e] = *(const u16x8*)&Qhi[go];
    pq[1][e] = *(const u16x8*)&Qmd[go];
    pk[0][e] = *(const u16x8*)&Khi[gi];
    pk[1][e] = *(const u16x8*)&Kmd[gi];
  }
  #pragma unroll
  for (int ot = 0; ot < 4; ot++)
    aLo[ot] = *(const bf16x8*)&Qlo[((size_t)b * NUM + o0 + obl + ot*16 + m) * CDIM + quad*8];
  #pragma unroll
  for (int it = 0; it < 4; it++)
    bLo[it] = *(const bf16x8*)&Klo[((size_t)b * NUM + i0 + ibl + it*16 + m) * CDIM + quad*8];

  for (int h = 0; h < 8; h++) {
    __syncthreads();   // readers of previous head done
    #pragma unroll
    for (int e = 0; e < 2; e++) {
      #pragma unroll
      for (int cp = 0; cp < 2; cp++) {
        *(u16x8*)&qsh[cp][srow + 64*e][schk] = pq[cp][e];
        *(u16x8*)&ksh[cp][srow + 64*e][schk] = pk[cp][e];
      }
    }
    __syncthreads();
    bf16x8 aLoN[4], bLoN[4];
    if (h < 7) {
      const int coff = (h + 1) * 32;
      #pragma unroll
      for (int e = 0; e < 2; e++) {
        const size_t go = ((size_t)b * NUM + o0 + srow + 64*e) * CDIM + coff + schk;
        const size_t gi = ((size_t)b * NUM + i0 + srow + 64*e) * CDIM + coff + schk;
        pq[0][e] = *(const u16x8*)&Qhi[go];
        pq[1][e] = *(const u16x8*)&Qmd[go];
        pk[0][e] = *(const u16x8*)&Khi[gi];
        pk[1][e] = *(const u16x8*)&Kmd[gi];
      }
      #pragma unroll
      for (int ot = 0; ot < 4; ot++)
        aLoN[ot] = *(const bf16x8*)&Qlo[((size_t)b * NUM + o0 + obl + ot*16 + m) * CDIM + coff + quad*8];
      #pragma unroll
      for (int it = 0; it < 4; it++)
        bLoN[it] = *(const bf16x8*)&Klo[((size_t)b * NUM + i0 + ibl + it*16 + m) * CDIM + coff + quad*8];
    }
    // compute head h: hi/md from LDS, lo from registers (prefetched last round)
    bf16x8 a[4][2];
    #pragma unroll
    for (int ot = 0; ot < 4; ot++)
      #pragma unroll
      for (int cp = 0; cp < 2; cp++)
        a[ot][cp] = *(const bf16x8*)&qsh[cp][obl + ot*16 + m][quad*8];
    #pragma unroll
    for (int it = 0; it < 4; it++) {
      const bf16x8 b0 = *(const bf16x8*)&ksh[0][ibl + it*16 + m][quad*8];
      const bf16x8 b1 = *(const bf16x8*)&ksh[1][ibl + it*16 + m][quad*8];
      #pragma unroll
      for (int ot = 0; ot < 4; ot++) {
        f32x4 c = (f32x4){0.f, 0.f, 0.f, 0.f};
        c = __builtin_amdgcn_mfma_f32_16x16x32_bf16(a[ot][0], b0, c, 0, 0, 0);      // hh
        c = __builtin_amdgcn_mfma_f32_16x16x32_bf16(a[ot][0], b1, c, 0, 0, 0);      // hm
        c = __builtin_amdgcn_mfma_f32_16x16x32_bf16(a[ot][1], b0, c, 0, 0, 0);      // mh
        c = __builtin_amdgcn_mfma_f32_16x16x32_bf16(a[ot][1], b1, c, 0, 0, 0);      // mm
        c = __builtin_amdgcn_mfma_f32_16x16x32_bf16(a[ot][0], bLo[it], c, 0, 0, 0); // hl
        c = __builtin_amdgcn_mfma_f32_16x16x32_bf16(aLo[ot], b0, c, 0, 0, 0);       // lh
        #pragma unroll
        for (int r = 0; r < 4; r++)
          ssum[ot][it][r] += __builtin_amdgcn_rcpf(1.0f + __builtin_amdgcn_exp2f(c[r] * SC));
      }
    }
    if (h < 7) {
      #pragma unroll
      for (int j = 0; j < 4; j++) { aLo[j] = aLoN[j]; bLo[j] = bLoN[j]; }
    }
  }
  const int ob = o0 + obl, ib = i0 + ibl;
  #pragma unroll
  for (int ot = 0; ot < 4; ot++)
    #pragma unroll
    for (int it = 0; it < 4; it++)
      #pragma unroll
      for (int r = 0; r < 4; r++) {
        const int row = ob + ot*16 + quad*4 + r;
        const int col = ib + it*16 + m;
        const size_t idx = ((size_t)b * NUM + row) * NUM + col;
        score[idx] = H0[idx] * ssum[ot][it][r] * 0.125f;
      }
}

// ---------------- fused: exact k-th largest (radix select on float bits, all >= 0)
// + W/H write + row count -> Dv. Vectorized uint4/float4 global access.
__global__ __launch_bounds__(256) void topk_apply_kernel(
    float* __restrict__ scoreW, float* __restrict__ Hout,
    const int* __restrict__ iterp, float* __restrict__ DvOut)
{
  const int row = blockIdx.x;
  __shared__ unsigned int hist[4][256];
  __shared__ unsigned int cum[257];
  __shared__ unsigned int s_sel, s_rem;
  __shared__ float red[4];
  const int t = threadIdx.x;
  const int wid = t >> 6, lane = t & 63;
  unsigned int* __restrict__ srow = (unsigned int*)scoreW + (size_t)row * NUM;

  const uint4 va = ((const uint4*)srow)[t*2];
  const uint4 vb = ((const uint4*)srow)[t*2+1];
  unsigned int v[8] = {va.x, va.y, va.z, va.w, vb.x, vb.y, vb.z, vb.w};

  const int it = iterp[0];
  int k = (int)((double)NUM * 0.1 * (double)(NUM_LAYER - 1 - it) + 0.5);
  if (k < 1) k = 1;
  if (k > NUM) k = NUM;

  unsigned int prefix = 0;
  unsigned int rem = (unsigned int)k;
  unsigned int* hflat = &hist[0][0];

  for (int pass = 3; pass >= 0; pass--) {
    const int shift = pass * 8;
    const unsigned int pmask = (pass == 3) ? 0u : (0xFFFFFFFFu << (shift + 8));
    #pragma unroll
    for (int j = 0; j < 4; j++) hflat[t + 256*j] = 0;
    __syncthreads();
    unsigned int zc = 0;
    #pragma unroll
    for (int j = 0; j < 8; j++) {
      unsigned int val = v[j];
      if ((val & pmask) == prefix) {
        unsigned int bin = (val >> shift) & 255u;
        if (bin) atomicAdd(&hist[wid][bin], 1u);
        else zc++;
      }
    }
    #pragma unroll
    for (int off = 32; off > 0; off >>= 1) zc += __shfl_down(zc, off, 64);
    if (lane == 0 && zc) atomicAdd(&hist[wid][0], zc);
    __syncthreads();
    if (t < 64) {
      unsigned int T[4], s[4];
      #pragma unroll
      for (int q = 0; q < 4; q++)
        T[q] = hist[0][t*4+q] + hist[1][t*4+q] + hist[2][t*4+q] + hist[3][t*4+q];
      s[3] = T[3];
      s[2] = T[2] + s[3];
      s[1] = T[1] + s[2];
      s[0] = T[0] + s[1];
      unsigned int tot = s[0];
      #pragma unroll
      for (int off = 1; off < 64; off <<= 1) {
        unsigned int y = __shfl_down(tot, off, 64);
        if (lane + off < 64) tot += y;
      }
      const unsigned int above_chunk = tot - s[0];
      #pragma unroll
      for (int q = 0; q < 4; q++) cum[t*4+q] = s[q] + above_chunk;
      if (t == 0) cum[256] = 0;
    }
    __syncthreads();
    unsigned int c = cum[t], above = cum[t + 1];
    if (c >= rem && above < rem) { s_sel = (unsigned int)t; s_rem = rem - above; }
    __syncthreads();
    prefix |= (s_sel << shift);
    rem = s_rem;
    __syncthreads();
  }

  const unsigned int amin = prefix;
  float* __restrict__ Hrow = Hout + (size_t)row * NUM;
  unsigned int w[8];
  float hh[8];
  float cnt = 0.0f;
  #pragma unroll
  for (int j = 0; j < 8; j++) {
    w[j] = (v[j] >= amin) ? v[j] : 0u;
    hh[j] = (w[j] != 0u) ? 1.0f : 0.0f;
    cnt += hh[j];
  }
  ((uint4*)srow)[t*2]   = make_uint4(w[0], w[1], w[2], w[3]);
  ((uint4*)srow)[t*2+1] = make_uint4(w[4], w[5], w[6], w[7]);
  ((float4*)Hrow)[t*2]   = make_float4(hh[0], hh[1], hh[2], hh[3]);
  ((float4*)Hrow)[t*2+1] = make_float4(hh[4], hh[5], hh[6], hh[7]);
  #pragma unroll
  for (int off = 32; off > 0; off >>= 1) cnt += __shfl_down(cnt, off, 64);
  if (lane == 0) red[wid] = cnt;
  __syncthreads();
  if (t == 0) {
    float tot = red[0] + red[1] + red[2] + red[3];
    DvOut[row] = 1.0f / (tot + 1e-10f);
  }
}

// ---------------- column partial sums over o; colH derived from W>0.
__global__ __launch_bounds__(256) void colsum_kernel(
    const float* __restrict__ Wmat,
    float* __restrict__ colH, float* __restrict__ colW)
{
  const int b = blockIdx.z;
  const int i = blockIdx.x * 256 + threadIdx.x;
  const int o0 = blockIdx.y * 128;
  float sh = 0.0f, sw = 0.0f;
  for (int o = 0; o < 128; o++) {
    size_t idx = ((size_t)b * NUM + o0 + o) * NUM + i;
    float w = Wmat[idx];
    sw += w;
    sh += (w > 0.0f) ? 1.0f : 0.0f;
  }
  atomicAdd(&colH[b * NUM + i], sh);
  atomicAdd(&colW[b * NUM + i], sw);
}

// ---------------- De = 1/(colH+eps); W_edge = colW / max(||colW||_2, 1e-12)
__global__ __launch_bounds__(1024) void finalize_kernel(
    const float* __restrict__ colH, const float* __restrict__ colW,
    float* __restrict__ De, float* __restrict__ We)
{
  const int b = blockIdx.x;
  const int t = threadIdx.x;
  float cw[2];
  float sq = 0.0f;
  #pragma unroll
  for (int j = 0; j < 2; j++) {
    int i = t + 1024*j;
    float ch = colH[b * NUM + i];
    De[b * NUM + i] = 1.0f / (ch + 1e-10f);
    cw[j] = colW[b * NUM + i];
    sq += cw[j] * cw[j];
  }
  for (int off = 32; off > 0; off >>= 1) sq += __shfl_down(sq, off, 64);
  __shared__ float red[16];
  __shared__ float s_nrm;
  if ((t & 63) == 0) red[t >> 6] = sq;
  __syncthreads();
  if (t == 0) {
    float tot = 0.0f;
    for (int i2 = 0; i2 < 16; i2++) tot += red[i2];
    s_nrm = fmaxf(sqrtf(tot), 1e-12f);
  }
  __syncthreads();
  #pragma unroll
  for (int j = 0; j < 2; j++)
    We[b * NUM + t + 1024*j] = cw[j] / s_nrm;
}

extern "C" void kernel_launch(void* const* d_in, const int* in_sizes, int n_in,
                              void* d_out, int out_size, void* d_ws, size_t ws_size,
                              hipStream_t stream) {
  const float* H0 = (const float*)d_in[0];
  const float* vf = (const float*)d_in[1];
  const float* ef = (const float*)d_in[2];
  const float* Wq = (const float*)d_in[3];
  const float* bq = (const float*)d_in[4];
  const float* Wk = (const float*)d_in[5];
  const float* bk = (const float*)d_in[6];
  const int* iter = (const int*)d_in[7];

  float* out = (float*)d_out;
  const size_t nH = (size_t)2 * NUM * NUM;
  float* Hout  = out;                 // (2,2048,2048)
  float* Wout  = out + nH;            // (2,2048,2048) — holds score temporarily
  float* DeOut = out + 2 * nH;        // (2,2048,1)
  float* DvOut = DeOut + 2 * NUM;     // (2,2048,1)
  float* WeOut = DvOut + 2 * NUM;     // (2,2048,1)

  float* colH = (float*)d_ws;         // 4096 floats
  float* colW = colH + 2 * NUM;       // 4096 floats

  // bf16 Q/K components (6 x 2MB = 12 MB) live in the H region until topk_apply
  const size_t nC = (size_t)2 * NUM * CDIM;
  unsigned short* base = (unsigned short*)Hout;
  unsigned short* Qhi = base;
  unsigned short* Qmd = base + nC;
  unsigned short* Qlo = base + 2 * nC;
  unsigned short* Khi = base + 3 * nC;
  unsigned short* Kmd = base + 4 * nC;
  unsigned short* Klo = base + 5 * nC;

  hipMemsetAsync(d_ws, 0, (size_t)2 * 2 * NUM * sizeof(float), stream);

  proj_kernel<<<dim3(NUM/64, CDIM/64, 4), 256, 0, stream>>>(
      Wq, bq, Wk, bk, vf, ef, Qhi, Qmd, Qlo, Khi, Kmd, Klo);
  score_kernel<<<dim3(NUM/128, NUM/128, 2), 256, 0, stream>>>(
      Qhi, Qmd, Qlo, Khi, Kmd, Klo, H0, Wout);
  topk_apply_kernel<<<dim3(2 * NUM), 256, 0, stream>>>(Wout, Hout, iter, DvOut);
  colsum_kernel<<<dim3(NUM/256, NUM/128, 2), 256, 0, stream>>>(Wout, colH, colW);
  finalize_kernel<<<dim3(2), 1024, 0, stream>>>(colH, colW, DeOut, WeOut);
}

// Round 12
// 206.368 us; speedup vs baseline: 1.0741x; 1.0741x over previous
//
#include <hip/hip_runtime.h>
#include <math.h>

#define NUM 2048
#define CDIM 256
#define NUM_LAYER 4

typedef short bf16x8 __attribute__((ext_vector_type(8)));
typedef unsigned short u16x8 __attribute__((ext_vector_type(8)));
typedef float f32x4 __attribute__((ext_vector_type(4)));

static __device__ __forceinline__ unsigned short f2bf(float f) {
  unsigned u = __float_as_uint(f);
  unsigned r = 0x7FFFu + ((u >> 16) & 1u);
  return (unsigned short)((u + r) >> 16);
}
static __device__ __forceinline__ float bf2f(unsigned short h) {
  return __uint_as_float(((unsigned)h) << 16);
}

// ---------------- projection + bf16 3-way split (x = hi + mid + lo, residuals
// exact). Epilogue transposes through LDS so component stores are coalesced.
__global__ __launch_bounds__(256) void proj_kernel(
    const float* __restrict__ Wq, const float* __restrict__ bq,
    const float* __restrict__ Wk, const float* __restrict__ bk,
    const float* __restrict__ vf, const float* __restrict__ ef,
    unsigned short* __restrict__ Qhi, unsigned short* __restrict__ Qmd,
    unsigned short* __restrict__ Qlo, unsigned short* __restrict__ Khi,
    unsigned short* __restrict__ Kmd, unsigned short* __restrict__ Klo)
{
  const int z = blockIdx.z;
  const int b = z >> 1, mm2 = z & 1;
  const float* __restrict__ Wmat = mm2 ? Wk : Wq;
  const float* __restrict__ bias = mm2 ? bk : bq;
  const float* __restrict__ x = (mm2 ? ef : vf) + (size_t)b * CDIM * NUM;
  unsigned short* __restrict__ ohi = mm2 ? Khi : Qhi;
  unsigned short* __restrict__ omd = mm2 ? Kmd : Qmd;
  unsigned short* __restrict__ olo = mm2 ? Klo : Qlo;

  const int n0 = blockIdx.x * 64;
  const int o0 = blockIdx.y * 64;
  __shared__ float Xs[32][65];
  __shared__ float Ws[64][33];
  __shared__ float T[64][69];
  const int t = threadIdx.x;
  const int tx = t & 15, ty = t >> 4;

  float acc[4][4];
  #pragma unroll
  for (int a = 0; a < 4; a++)
    #pragma unroll
    for (int c = 0; c < 4; c++) acc[a][c] = 0.0f;

  for (int cc = 0; cc < CDIM; cc += 32) {
    #pragma unroll
    for (int e = 0; e < 2; e++) {
      int f = t * 2 + e;
      int row = f >> 4, c4 = f & 15;
      const float4 v = *(const float4*)(&x[(size_t)(cc + row) * NUM + n0 + c4 * 4]);
      Xs[row][c4*4+0] = v.x; Xs[row][c4*4+1] = v.y;
      Xs[row][c4*4+2] = v.z; Xs[row][c4*4+3] = v.w;
    }
    #pragma unroll
    for (int e = 0; e < 2; e++) {
      int f = t * 2 + e;
      int row = f >> 3, c4 = f & 7;
      const float4 v = *(const float4*)(&Wmat[(size_t)(o0 + row) * CDIM + cc + c4 * 4]);
      Ws[row][c4*4+0] = v.x; Ws[row][c4*4+1] = v.y;
      Ws[row][c4*4+2] = v.z; Ws[row][c4*4+3] = v.w;
    }
    __syncthreads();
    #pragma unroll
    for (int kk = 0; kk < 32; kk++) {
      float xv[4], wv[4];
      #pragma unroll
      for (int j = 0; j < 4; j++) xv[j] = Xs[kk][tx*4+j];
      #pragma unroll
      for (int j = 0; j < 4; j++) wv[j] = Ws[ty*4+j][kk];
      #pragma unroll
      for (int oi = 0; oi < 4; oi++)
        #pragma unroll
        for (int ni = 0; ni < 4; ni++)
          acc[oi][ni] = fmaf(wv[oi], xv[ni], acc[oi][ni]);
    }
    __syncthreads();
  }
  float bb[4];
  #pragma unroll
  for (int oi = 0; oi < 4; oi++) bb[oi] = bias[o0 + ty*4 + oi];
  #pragma unroll
  for (int ni = 0; ni < 4; ni++)
    #pragma unroll
    for (int oi = 0; oi < 4; oi++)
      T[tx*4+ni][ty*4+oi] = acc[oi][ni] + bb[oi];
  __syncthreads();
  const int n_l = t >> 2;
  const int oc  = (t & 3) * 16;
  float xv[16];
  #pragma unroll
  for (int j = 0; j < 16; j++) xv[j] = T[n_l][oc + j];
  unsigned short hi[16], md[16], lo[16];
  #pragma unroll
  for (int j = 0; j < 16; j++) {
    unsigned short h = f2bf(xv[j]);
    float r1 = xv[j] - bf2f(h);
    unsigned short mdj = f2bf(r1);
    float r2 = r1 - bf2f(mdj);
    hi[j] = h; md[j] = mdj; lo[j] = f2bf(r2);
  }
  const size_t gb = ((size_t)b * NUM + n0 + n_l) * CDIM + o0 + oc;
  *(u16x8*)&ohi[gb]   = *(u16x8*)&hi[0];
  *(u16x8*)&ohi[gb+8] = *(u16x8*)&hi[8];
  *(u16x8*)&omd[gb]   = *(u16x8*)&md[0];
  *(u16x8*)&omd[gb+8] = *(u16x8*)&md[8];
  *(u16x8*)&olo[gb]   = *(u16x8*)&lo[0];
  *(u16x8*)&olo[gb+8] = *(u16x8*)&lo[8];
}

// ---------------- score via MFMA (bf16 3-way split, 6 products = fp32-equiv).
// R9 structure (128x128 tile, all 3 comps LDS-staged, stride 36, reg-prefetch)
// with ONE change: 512 threads / 8 waves per block, wave tile 64(o)x32(i).
// 2 blocks/CU x 8 waves = 16 waves/CU (2x R9 occupancy), same LDS + traffic.
// Per-element FMA order identical to R9 -> bit-identical scores.
__global__ __launch_bounds__(512, 2) void score_kernel(
    const unsigned short* __restrict__ Qhi, const unsigned short* __restrict__ Qmd,
    const unsigned short* __restrict__ Qlo, const unsigned short* __restrict__ Khi,
    const unsigned short* __restrict__ Kmd, const unsigned short* __restrict__ Klo,
    const float* __restrict__ H0, float* __restrict__ score)
{
  const int b = blockIdx.z;
  const int i0 = blockIdx.x * 128;
  const int o0 = blockIdx.y * 128;
  const int t = threadIdx.x, lane = t & 63, wave = t >> 6;
  const int m = lane & 15, quad = lane >> 4;
  const int obl = (wave & 1) * 64;    // local o base of this wave (64 rows)
  const int ibl = (wave >> 1) * 32;   // local i base (32 cols)

  __shared__ unsigned short qsh[3][128][36];
  __shared__ unsigned short ksh[3][128][36];

  const int srow = t >> 2;            // 0..127
  const int schk = (t & 3) * 8;       // short offset within 32-col row

  f32x4 ssum[4][2];
  #pragma unroll
  for (int a = 0; a < 4; a++)
    #pragma unroll
    for (int c = 0; c < 2; c++) ssum[a][c] = (f32x4){0.f, 0.f, 0.f, 0.f};

  const float SC = -1.4426950408889634f * 0.17677669529663687f;  // -log2(e)/sqrt(32)

  u16x8 pq[3], pk[3];
  // prologue: head 0 fragments to registers (one u16x8 per comp per side)
  {
    const size_t go = ((size_t)b * NUM + o0 + srow) * CDIM + schk;
    const size_t gi = ((size_t)b * NUM + i0 + srow) * CDIM + schk;
    pq[0] = *(const u16x8*)&Qhi[go];
    pq[1] = *(const u16x8*)&Qmd[go];
    pq[2] = *(const u16x8*)&Qlo[go];
    pk[0] = *(const u16x8*)&Khi[gi];
    pk[1] = *(const u16x8*)&Kmd[gi];
    pk[2] = *(const u16x8*)&Klo[gi];
  }

  for (int h = 0; h < 8; h++) {
    __syncthreads();   // readers of previous head done
    #pragma unroll
    for (int cp = 0; cp < 3; cp++) {
      *(u16x8*)&qsh[cp][srow][schk] = pq[cp];
      *(u16x8*)&ksh[cp][srow][schk] = pk[cp];
    }
    __syncthreads();
    if (h < 7) {
      const int coff = (h + 1) * 32;
      const size_t go = ((size_t)b * NUM + o0 + srow) * CDIM + coff + schk;
      const size_t gi = ((size_t)b * NUM + i0 + srow) * CDIM + coff + schk;
      pq[0] = *(const u16x8*)&Qhi[go];
      pq[1] = *(const u16x8*)&Qmd[go];
      pq[2] = *(const u16x8*)&Qlo[go];
      pk[0] = *(const u16x8*)&Khi[gi];
      pk[1] = *(const u16x8*)&Kmd[gi];
      pk[2] = *(const u16x8*)&Klo[gi];
    }
    // compute head h from LDS
    bf16x8 a[4][3];
    #pragma unroll
    for (int ot = 0; ot < 4; ot++)
      #pragma unroll
      for (int cp = 0; cp < 3; cp++)
        a[ot][cp] = *(const bf16x8*)&qsh[cp][obl + ot*16 + m][quad*8];
    #pragma unroll
    for (int it = 0; it < 2; it++) {
      const bf16x8 b0 = *(const bf16x8*)&ksh[0][ibl + it*16 + m][quad*8];
      const bf16x8 b1 = *(const bf16x8*)&ksh[1][ibl + it*16 + m][quad*8];
      const bf16x8 b2 = *(const bf16x8*)&ksh[2][ibl + it*16 + m][quad*8];
      #pragma unroll
      for (int ot = 0; ot < 4; ot++) {
        f32x4 c = (f32x4){0.f, 0.f, 0.f, 0.f};
        c = __builtin_amdgcn_mfma_f32_16x16x32_bf16(a[ot][0], b0, c, 0, 0, 0); // hh
        c = __builtin_amdgcn_mfma_f32_16x16x32_bf16(a[ot][0], b1, c, 0, 0, 0); // hm
        c = __builtin_amdgcn_mfma_f32_16x16x32_bf16(a[ot][1], b0, c, 0, 0, 0); // mh
        c = __builtin_amdgcn_mfma_f32_16x16x32_bf16(a[ot][1], b1, c, 0, 0, 0); // mm
        c = __builtin_amdgcn_mfma_f32_16x16x32_bf16(a[ot][0], b2, c, 0, 0, 0); // hl
        c = __builtin_amdgcn_mfma_f32_16x16x32_bf16(a[ot][2], b0, c, 0, 0, 0); // lh
        #pragma unroll
        for (int r = 0; r < 4; r++)
          ssum[ot][it][r] += __builtin_amdgcn_rcpf(1.0f + __builtin_amdgcn_exp2f(c[r] * SC));
      }
    }
  }
  const int ob = o0 + obl, ib = i0 + ibl;
  #pragma unroll
  for (int ot = 0; ot < 4; ot++)
    #pragma unroll
    for (int it = 0; it < 2; it++)
      #pragma unroll
      for (int r = 0; r < 4; r++) {
        const int row = ob + ot*16 + quad*4 + r;
        const int col = ib + it*16 + m;
        const size_t idx = ((size_t)b * NUM + row) * NUM + col;
        score[idx] = H0[idx] * ssum[ot][it][r] * 0.125f;
      }
}

// ---------------- fused: exact k-th largest (radix select on float bits, all >= 0)
// + W/H write + row count -> Dv. Vectorized uint4/float4 global access.
__global__ __launch_bounds__(256) void topk_apply_kernel(
    float* __restrict__ scoreW, float* __restrict__ Hout,
    const int* __restrict__ iterp, float* __restrict__ DvOut)
{
  const int row = blockIdx.x;
  __shared__ unsigned int hist[4][256];
  __shared__ unsigned int cum[257];
  __shared__ unsigned int s_sel, s_rem;
  __shared__ float red[4];
  const int t = threadIdx.x;
  const int wid = t >> 6, lane = t & 63;
  unsigned int* __restrict__ srow = (unsigned int*)scoreW + (size_t)row * NUM;

  const uint4 va = ((const uint4*)srow)[t*2];
  const uint4 vb = ((const uint4*)srow)[t*2+1];
  unsigned int v[8] = {va.x, va.y, va.z, va.w, vb.x, vb.y, vb.z, vb.w};

  const int it = iterp[0];
  int k = (int)((double)NUM * 0.1 * (double)(NUM_LAYER - 1 - it) + 0.5);
  if (k < 1) k = 1;
  if (k > NUM) k = NUM;

  unsigned int prefix = 0;
  unsigned int rem = (unsigned int)k;
  unsigned int* hflat = &hist[0][0];

  for (int pass = 3; pass >= 0; pass--) {
    const int shift = pass * 8;
    const unsigned int pmask = (pass == 3) ? 0u : (0xFFFFFFFFu << (shift + 8));
    #pragma unroll
    for (int j = 0; j < 4; j++) hflat[t + 256*j] = 0;
    __syncthreads();
    unsigned int zc = 0;
    #pragma unroll
    for (int j = 0; j < 8; j++) {
      unsigned int val = v[j];
      if ((val & pmask) == prefix) {
        unsigned int bin = (val >> shift) & 255u;
        if (bin) atomicAdd(&hist[wid][bin], 1u);
        else zc++;
      }
    }
    #pragma unroll
    for (int off = 32; off > 0; off >>= 1) zc += __shfl_down(zc, off, 64);
    if (lane == 0 && zc) atomicAdd(&hist[wid][0], zc);
    __syncthreads();
    if (t < 64) {
      unsigned int T[4], s[4];
      #pragma unroll
      for (int q = 0; q < 4; q++)
        T[q] = hist[0][t*4+q] + hist[1][t*4+q] + hist[2][t*4+q] + hist[3][t*4+q];
      s[3] = T[3];
      s[2] = T[2] + s[3];
      s[1] = T[1] + s[2];
      s[0] = T[0] + s[1];
      unsigned int tot = s[0];
      #pragma unroll
      for (int off = 1; off < 64; off <<= 1) {
        unsigned int y = __shfl_down(tot, off, 64);
        if (lane + off < 64) tot += y;
      }
      const unsigned int above_chunk = tot - s[0];
      #pragma unroll
      for (int q = 0; q < 4; q++) cum[t*4+q] = s[q] + above_chunk;
      if (t == 0) cum[256] = 0;
    }
    __syncthreads();
    unsigned int c = cum[t], above = cum[t + 1];
    if (c >= rem && above < rem) { s_sel = (unsigned int)t; s_rem = rem - above; }
    __syncthreads();
    prefix |= (s_sel << shift);
    rem = s_rem;
    __syncthreads();
  }

  const unsigned int amin = prefix;
  float* __restrict__ Hrow = Hout + (size_t)row * NUM;
  unsigned int w[8];
  float hh[8];
  float cnt = 0.0f;
  #pragma unroll
  for (int j = 0; j < 8; j++) {
    w[j] = (v[j] >= amin) ? v[j] : 0u;
    hh[j] = (w[j] != 0u) ? 1.0f : 0.0f;
    cnt += hh[j];
  }
  ((uint4*)srow)[t*2]   = make_uint4(w[0], w[1], w[2], w[3]);
  ((uint4*)srow)[t*2+1] = make_uint4(w[4], w[5], w[6], w[7]);
  ((float4*)Hrow)[t*2]   = make_float4(hh[0], hh[1], hh[2], hh[3]);
  ((float4*)Hrow)[t*2+1] = make_float4(hh[4], hh[5], hh[6], hh[7]);
  #pragma unroll
  for (int off = 32; off > 0; off >>= 1) cnt += __shfl_down(cnt, off, 64);
  if (lane == 0) red[wid] = cnt;
  __syncthreads();
  if (t == 0) {
    float tot = red[0] + red[1] + red[2] + red[3];
    DvOut[row] = 1.0f / (tot + 1e-10f);
  }
}

// ---------------- column partial sums over o; colH derived from W>0.
__global__ __launch_bounds__(256) void colsum_kernel(
    const float* __restrict__ Wmat,
    float* __restrict__ colH, float* __restrict__ colW)
{
  const int b = blockIdx.z;
  const int i = blockIdx.x * 256 + threadIdx.x;
  const int o0 = blockIdx.y * 128;
  float sh = 0.0f, sw = 0.0f;
  for (int o = 0; o < 128; o++) {
    size_t idx = ((size_t)b * NUM + o0 + o) * NUM + i;
    float w = Wmat[idx];
    sw += w;
    sh += (w > 0.0f) ? 1.0f : 0.0f;
  }
  atomicAdd(&colH[b * NUM + i], sh);
  atomicAdd(&colW[b * NUM + i], sw);
}

// ---------------- De = 1/(colH+eps); W_edge = colW / max(||colW||_2, 1e-12)
__global__ __launch_bounds__(1024) void finalize_kernel(
    const float* __restrict__ colH, const float* __restrict__ colW,
    float* __restrict__ De, float* __restrict__ We)
{
  const int b = blockIdx.x;
  const int t = threadIdx.x;
  float cw[2];
  float sq = 0.0f;
  #pragma unroll
  for (int j = 0; j < 2; j++) {
    int i = t + 1024*j;
    float ch = colH[b * NUM + i];
    De[b * NUM + i] = 1.0f / (ch + 1e-10f);
    cw[j] = colW[b * NUM + i];
    sq += cw[j] * cw[j];
  }
  for (int off = 32; off > 0; off >>= 1) sq += __shfl_down(sq, off, 64);
  __shared__ float red[16];
  __shared__ float s_nrm;
  if ((t & 63) == 0) red[t >> 6] = sq;
  __syncthreads();
  if (t == 0) {
    float tot = 0.0f;
    for (int i2 = 0; i2 < 16; i2++) tot += red[i2];
    s_nrm = fmaxf(sqrtf(tot), 1e-12f);
  }
  __syncthreads();
  #pragma unroll
  for (int j = 0; j < 2; j++)
    We[b * NUM + t + 1024*j] = cw[j] / s_nrm;
}

extern "C" void kernel_launch(void* const* d_in, const int* in_sizes, int n_in,
                              void* d_out, int out_size, void* d_ws, size_t ws_size,
                              hipStream_t stream) {
  const float* H0 = (const float*)d_in[0];
  const float* vf = (const float*)d_in[1];
  const float* ef = (const float*)d_in[2];
  const float* Wq = (const float*)d_in[3];
  const float* bq = (const float*)d_in[4];
  const float* Wk = (const float*)d_in[5];
  const float* bk = (const float*)d_in[6];
  const int* iter = (const int*)d_in[7];

  float* out = (float*)d_out;
  const size_t nH = (size_t)2 * NUM * NUM;
  float* Hout  = out;                 // (2,2048,2048)
  float* Wout  = out + nH;            // (2,2048,2048) — holds score temporarily
  float* DeOut = out + 2 * nH;        // (2,2048,1)
  float* DvOut = DeOut + 2 * NUM;     // (2,2048,1)
  float* WeOut = DvOut + 2 * NUM;     // (2,2048,1)

  float* colH = (float*)d_ws;         // 4096 floats
  float* colW = colH + 2 * NUM;       // 4096 floats

  // bf16 Q/K components (6 x 2MB = 12 MB) live in the H region until topk_apply
  const size_t nC = (size_t)2 * NUM * CDIM;
  unsigned short* base = (unsigned short*)Hout;
  unsigned short* Qhi = base;
  unsigned short* Qmd = base + nC;
  unsigned short* Qlo = base + 2 * nC;
  unsigned short* Khi = base + 3 * nC;
  unsigned short* Kmd = base + 4 * nC;
  unsigned short* Klo = base + 5 * nC;

  hipMemsetAsync(d_ws, 0, (size_t)2 * 2 * NUM * sizeof(float), stream);

  proj_kernel<<<dim3(NUM/64, CDIM/64, 4), 256, 0, stream>>>(
      Wq, bq, Wk, bk, vf, ef, Qhi, Qmd, Qlo, Khi, Kmd, Klo);
  score_kernel<<<dim3(NUM/128, NUM/128, 2), 512, 0, stream>>>(
      Qhi, Qmd, Qlo, Khi, Kmd, Klo, H0, Wout);
  topk_apply_kernel<<<dim3(2 * NUM), 256, 0, stream>>>(Wout, Hout, iter, DvOut);
  colsum_kernel<<<dim3(NUM/256, NUM/128, 2), 256, 0, stream>>>(Wout, colH, colW);
  finalize_kernel<<<dim3(2), 1024, 0, stream>>>(colH, colW, DeOut, WeOut);
}

// Round 13
// 200.327 us; speedup vs baseline: 1.1065x; 1.0302x over previous
//
#include <hip/hip_runtime.h>
#include <math.h>

#define NUM 2048
#define CDIM 256
#define NUM_LAYER 4

typedef short bf16x8 __attribute__((ext_vector_type(8)));
typedef unsigned short u16x8 __attribute__((ext_vector_type(8)));
typedef float f32x4 __attribute__((ext_vector_type(4)));

static __device__ __forceinline__ unsigned short f2bf(float f) {
  unsigned u = __float_as_uint(f);
  unsigned r = 0x7FFFu + ((u >> 16) & 1u);
  return (unsigned short)((u + r) >> 16);
}
static __device__ __forceinline__ float bf2f(unsigned short h) {
  return __uint_as_float(((unsigned)h) << 16);
}

// ---------------- projection + bf16 3-way split (x = hi + mid + lo, residuals
// exact). Epilogue transposes through LDS so component stores are coalesced.
__global__ __launch_bounds__(256) void proj_kernel(
    const float* __restrict__ Wq, const float* __restrict__ bq,
    const float* __restrict__ Wk, const float* __restrict__ bk,
    const float* __restrict__ vf, const float* __restrict__ ef,
    unsigned short* __restrict__ Qhi, unsigned short* __restrict__ Qmd,
    unsigned short* __restrict__ Qlo, unsigned short* __restrict__ Khi,
    unsigned short* __restrict__ Kmd, unsigned short* __restrict__ Klo)
{
  const int z = blockIdx.z;
  const int b = z >> 1, mm2 = z & 1;
  const float* __restrict__ Wmat = mm2 ? Wk : Wq;
  const float* __restrict__ bias = mm2 ? bk : bq;
  const float* __restrict__ x = (mm2 ? ef : vf) + (size_t)b * CDIM * NUM;
  unsigned short* __restrict__ ohi = mm2 ? Khi : Qhi;
  unsigned short* __restrict__ omd = mm2 ? Kmd : Qmd;
  unsigned short* __restrict__ olo = mm2 ? Klo : Qlo;

  const int n0 = blockIdx.x * 64;
  const int o0 = blockIdx.y * 64;
  __shared__ float Xs[32][65];
  __shared__ float Ws[64][33];
  __shared__ float T[64][69];
  const int t = threadIdx.x;
  const int tx = t & 15, ty = t >> 4;

  float acc[4][4];
  #pragma unroll
  for (int a = 0; a < 4; a++)
    #pragma unroll
    for (int c = 0; c < 4; c++) acc[a][c] = 0.0f;

  for (int cc = 0; cc < CDIM; cc += 32) {
    #pragma unroll
    for (int e = 0; e < 2; e++) {
      int f = t * 2 + e;
      int row = f >> 4, c4 = f & 15;
      const float4 v = *(const float4*)(&x[(size_t)(cc + row) * NUM + n0 + c4 * 4]);
      Xs[row][c4*4+0] = v.x; Xs[row][c4*4+1] = v.y;
      Xs[row][c4*4+2] = v.z; Xs[row][c4*4+3] = v.w;
    }
    #pragma unroll
    for (int e = 0; e < 2; e++) {
      int f = t * 2 + e;
      int row = f >> 3, c4 = f & 7;
      const float4 v = *(const float4*)(&Wmat[(size_t)(o0 + row) * CDIM + cc + c4 * 4]);
      Ws[row][c4*4+0] = v.x; Ws[row][c4*4+1] = v.y;
      Ws[row][c4*4+2] = v.z; Ws[row][c4*4+3] = v.w;
    }
    __syncthreads();
    #pragma unroll
    for (int kk = 0; kk < 32; kk++) {
      float xv[4], wv[4];
      #pragma unroll
      for (int j = 0; j < 4; j++) xv[j] = Xs[kk][tx*4+j];
      #pragma unroll
      for (int j = 0; j < 4; j++) wv[j] = Ws[ty*4+j][kk];
      #pragma unroll
      for (int oi = 0; oi < 4; oi++)
        #pragma unroll
        for (int ni = 0; ni < 4; ni++)
          acc[oi][ni] = fmaf(wv[oi], xv[ni], acc[oi][ni]);
    }
    __syncthreads();
  }
  float bb[4];
  #pragma unroll
  for (int oi = 0; oi < 4; oi++) bb[oi] = bias[o0 + ty*4 + oi];
  #pragma unroll
  for (int ni = 0; ni < 4; ni++)
    #pragma unroll
    for (int oi = 0; oi < 4; oi++)
      T[tx*4+ni][ty*4+oi] = acc[oi][ni] + bb[oi];
  __syncthreads();
  const int n_l = t >> 2;
  const int oc  = (t & 3) * 16;
  float xv[16];
  #pragma unroll
  for (int j = 0; j < 16; j++) xv[j] = T[n_l][oc + j];
  unsigned short hi[16], md[16], lo[16];
  #pragma unroll
  for (int j = 0; j < 16; j++) {
    unsigned short h = f2bf(xv[j]);
    float r1 = xv[j] - bf2f(h);
    unsigned short mdj = f2bf(r1);
    float r2 = r1 - bf2f(mdj);
    hi[j] = h; md[j] = mdj; lo[j] = f2bf(r2);
  }
  const size_t gb = ((size_t)b * NUM + n0 + n_l) * CDIM + o0 + oc;
  *(u16x8*)&ohi[gb]   = *(u16x8*)&hi[0];
  *(u16x8*)&ohi[gb+8] = *(u16x8*)&hi[8];
  *(u16x8*)&omd[gb]   = *(u16x8*)&md[0];
  *(u16x8*)&omd[gb+8] = *(u16x8*)&md[8];
  *(u16x8*)&olo[gb]   = *(u16x8*)&lo[0];
  *(u16x8*)&olo[gb+8] = *(u16x8*)&lo[8];
}

// ---------------- score via MFMA (bf16 3-way split, 6 products = fp32-equiv).
// 512 threads / 8 waves, 128x128 tile, wave tile 64(o)x32(i), all comps staged,
// stride-36 LDS, reg-prefetch next head. Measured 52 us (R12).
__global__ __launch_bounds__(512, 2) void score_kernel(
    const unsigned short* __restrict__ Qhi, const unsigned short* __restrict__ Qmd,
    const unsigned short* __restrict__ Qlo, const unsigned short* __restrict__ Khi,
    const unsigned short* __restrict__ Kmd, const unsigned short* __restrict__ Klo,
    const float* __restrict__ H0, float* __restrict__ score)
{
  const int b = blockIdx.z;
  const int i0 = blockIdx.x * 128;
  const int o0 = blockIdx.y * 128;
  const int t = threadIdx.x, lane = t & 63, wave = t >> 6;
  const int m = lane & 15, quad = lane >> 4;
  const int obl = (wave & 1) * 64;
  const int ibl = (wave >> 1) * 32;

  __shared__ unsigned short qsh[3][128][36];
  __shared__ unsigned short ksh[3][128][36];

  const int srow = t >> 2;
  const int schk = (t & 3) * 8;

  f32x4 ssum[4][2];
  #pragma unroll
  for (int a = 0; a < 4; a++)
    #pragma unroll
    for (int c = 0; c < 2; c++) ssum[a][c] = (f32x4){0.f, 0.f, 0.f, 0.f};

  const float SC = -1.4426950408889634f * 0.17677669529663687f;  // -log2(e)/sqrt(32)

  u16x8 pq[3], pk[3];
  {
    const size_t go = ((size_t)b * NUM + o0 + srow) * CDIM + schk;
    const size_t gi = ((size_t)b * NUM + i0 + srow) * CDIM + schk;
    pq[0] = *(const u16x8*)&Qhi[go];
    pq[1] = *(const u16x8*)&Qmd[go];
    pq[2] = *(const u16x8*)&Qlo[go];
    pk[0] = *(const u16x8*)&Khi[gi];
    pk[1] = *(const u16x8*)&Kmd[gi];
    pk[2] = *(const u16x8*)&Klo[gi];
  }

  for (int h = 0; h < 8; h++) {
    __syncthreads();
    #pragma unroll
    for (int cp = 0; cp < 3; cp++) {
      *(u16x8*)&qsh[cp][srow][schk] = pq[cp];
      *(u16x8*)&ksh[cp][srow][schk] = pk[cp];
    }
    __syncthreads();
    if (h < 7) {
      const int coff = (h + 1) * 32;
      const size_t go = ((size_t)b * NUM + o0 + srow) * CDIM + coff + schk;
      const size_t gi = ((size_t)b * NUM + i0 + srow) * CDIM + coff + schk;
      pq[0] = *(const u16x8*)&Qhi[go];
      pq[1] = *(const u16x8*)&Qmd[go];
      pq[2] = *(const u16x8*)&Qlo[go];
      pk[0] = *(const u16x8*)&Khi[gi];
      pk[1] = *(const u16x8*)&Kmd[gi];
      pk[2] = *(const u16x8*)&Klo[gi];
    }
    bf16x8 a[4][3];
    #pragma unroll
    for (int ot = 0; ot < 4; ot++)
      #pragma unroll
      for (int cp = 0; cp < 3; cp++)
        a[ot][cp] = *(const bf16x8*)&qsh[cp][obl + ot*16 + m][quad*8];
    #pragma unroll
    for (int it = 0; it < 2; it++) {
      const bf16x8 b0 = *(const bf16x8*)&ksh[0][ibl + it*16 + m][quad*8];
      const bf16x8 b1 = *(const bf16x8*)&ksh[1][ibl + it*16 + m][quad*8];
      const bf16x8 b2 = *(const bf16x8*)&ksh[2][ibl + it*16 + m][quad*8];
      #pragma unroll
      for (int ot = 0; ot < 4; ot++) {
        f32x4 c = (f32x4){0.f, 0.f, 0.f, 0.f};
        c = __builtin_amdgcn_mfma_f32_16x16x32_bf16(a[ot][0], b0, c, 0, 0, 0); // hh
        c = __builtin_amdgcn_mfma_f32_16x16x32_bf16(a[ot][0], b1, c, 0, 0, 0); // hm
        c = __builtin_amdgcn_mfma_f32_16x16x32_bf16(a[ot][1], b0, c, 0, 0, 0); // mh
        c = __builtin_amdgcn_mfma_f32_16x16x32_bf16(a[ot][1], b1, c, 0, 0, 0); // mm
        c = __builtin_amdgcn_mfma_f32_16x16x32_bf16(a[ot][0], b2, c, 0, 0, 0); // hl
        c = __builtin_amdgcn_mfma_f32_16x16x32_bf16(a[ot][2], b0, c, 0, 0, 0); // lh
        #pragma unroll
        for (int r = 0; r < 4; r++)
          ssum[ot][it][r] += __builtin_amdgcn_rcpf(1.0f + __builtin_amdgcn_exp2f(c[r] * SC));
      }
    }
  }
  const int ob = o0 + obl, ib = i0 + ibl;
  #pragma unroll
  for (int ot = 0; ot < 4; ot++)
    #pragma unroll
    for (int it = 0; it < 2; it++)
      #pragma unroll
      for (int r = 0; r < 4; r++) {
        const int row = ob + ot*16 + quad*4 + r;
        const int col = ib + it*16 + m;
        const size_t idx = ((size_t)b * NUM + row) * NUM + col;
        score[idx] = H0[idx] * ssum[ot][it][r] * 0.125f;
      }
}

// ---------------- barrier-free fused topk+apply: ONE WAVE PER ROW.
// Each wave: private 1KB LDS histogram, 4-pass radix select (zero, count,
// 64-lane suffix scan, ballot+shfl select — all wave-internal, no s_barrier),
// then W/H/Dv write. Same select invariant as the verified block version.
__global__ __launch_bounds__(256) void topk_apply_kernel(
    float* __restrict__ scoreW, float* __restrict__ Hout,
    const int* __restrict__ iterp, float* __restrict__ DvOut)
{
  const int wave = threadIdx.x >> 6, lane = threadIdx.x & 63;
  const int row = blockIdx.x * 4 + wave;
  __shared__ unsigned int hist_all[4][256];
  unsigned int* __restrict__ h = hist_all[wave];
  unsigned int* __restrict__ srow = (unsigned int*)scoreW + (size_t)row * NUM;
  float* __restrict__ Hrow = Hout + (size_t)row * NUM;

  uint4 v[8];
  #pragma unroll
  for (int q = 0; q < 8; q++) v[q] = ((const uint4*)srow)[lane + 64*q];

  const int it = iterp[0];
  int k = (int)((double)NUM * 0.1 * (double)(NUM_LAYER - 1 - it) + 0.5);
  if (k < 1) k = 1;
  if (k > NUM) k = NUM;

  unsigned int prefix = 0;
  unsigned int rem = (unsigned int)k;

  for (int pass = 3; pass >= 0; pass--) {
    const int shift = pass * 8;
    const unsigned int pmask = (pass == 3) ? 0u : (0xFFFFFFFFu << (shift + 8));
    *(uint4*)&h[lane*4] = make_uint4(0u, 0u, 0u, 0u);
    __threadfence_block();
    unsigned int zc = 0;
    #pragma unroll
    for (int q = 0; q < 8; q++) {
      const unsigned int vv[4] = {v[q].x, v[q].y, v[q].z, v[q].w};
      #pragma unroll
      for (int e = 0; e < 4; e++) {
        unsigned int val = vv[e];
        if ((val & pmask) == prefix) {
          unsigned int bin = (val >> shift) & 255u;
          if (bin) atomicAdd(&h[bin], 1u);
          else zc++;
        }
      }
    }
    #pragma unroll
    for (int off = 32; off > 0; off >>= 1) zc += __shfl_down(zc, off, 64);
    if (lane == 0) h[0] = zc;
    __threadfence_block();
    // 256-bin suffix scan: lane owns bins [lane*4, lane*4+3]
    const uint4 T = *(const uint4*)&h[lane*4];
    unsigned int s3 = T.w;
    unsigned int s2 = T.z + s3;
    unsigned int s1 = T.y + s2;
    unsigned int s0 = T.x + s1;
    unsigned int tot = s0;
    #pragma unroll
    for (int off = 1; off < 64; off <<= 1) {
      unsigned int y = __shfl_down(tot, off, 64);
      if (lane + off < 64) tot += y;
    }
    const unsigned int ac = tot - s0;    // sum over lanes > lane
    const unsigned int cum[4]   = {s0 + ac, s1 + ac, s2 + ac, s3 + ac};
    const unsigned int above[4] = {s1 + ac, s2 + ac, s3 + ac, ac};
    int fq = -1;
    #pragma unroll
    for (int q = 0; q < 4; q++)
      if (cum[q] >= rem && above[q] < rem) fq = q;
    const unsigned long long mask = __ballot(fq >= 0);
    const int src = (int)(__ffsll((long long)mask) - 1);
    const unsigned int selbin = (fq >= 0) ? (unsigned int)(lane*4 + fq) : 0u;
    const unsigned int nrem   = (fq >= 0) ? (rem - above[fq]) : 0u;
    const unsigned int sel = (unsigned int)__shfl((int)selbin, src, 64);
    rem = (unsigned int)__shfl((int)nrem, src, 64);
    prefix |= (sel << shift);
  }

  const unsigned int amin = prefix;
  float cnt = 0.0f;
  #pragma unroll
  for (int q = 0; q < 8; q++) {
    unsigned int w0 = (v[q].x >= amin) ? v[q].x : 0u;
    unsigned int w1 = (v[q].y >= amin) ? v[q].y : 0u;
    unsigned int w2 = (v[q].z >= amin) ? v[q].z : 0u;
    unsigned int w3 = (v[q].w >= amin) ? v[q].w : 0u;
    float h0 = (w0 != 0u) ? 1.0f : 0.0f;
    float h1 = (w1 != 0u) ? 1.0f : 0.0f;
    float h2 = (w2 != 0u) ? 1.0f : 0.0f;
    float h3 = (w3 != 0u) ? 1.0f : 0.0f;
    cnt += h0 + h1 + h2 + h3;
    ((uint4*)srow)[lane + 64*q] = make_uint4(w0, w1, w2, w3);
    ((float4*)Hrow)[lane + 64*q] = make_float4(h0, h1, h2, h3);
  }
  #pragma unroll
  for (int off = 32; off > 0; off >>= 1) cnt += __shfl_down(cnt, off, 64);
  if (lane == 0) DvOut[row] = 1.0f / (cnt + 1e-10f);
}

// ---------------- column partial sums over o; colH derived from W>0.
__global__ __launch_bounds__(256) void colsum_kernel(
    const float* __restrict__ Wmat,
    float* __restrict__ colH, float* __restrict__ colW)
{
  const int b = blockIdx.z;
  const int i = blockIdx.x * 256 + threadIdx.x;
  const int o0 = blockIdx.y * 64;
  float sh = 0.0f, sw = 0.0f;
  for (int o = 0; o < 64; o++) {
    size_t idx = ((size_t)b * NUM + o0 + o) * NUM + i;
    float w = Wmat[idx];
    sw += w;
    sh += (w > 0.0f) ? 1.0f : 0.0f;
  }
  atomicAdd(&colH[b * NUM + i], sh);
  atomicAdd(&colW[b * NUM + i], sw);
}

// ---------------- De = 1/(colH+eps); W_edge = colW / max(||colW||_2, 1e-12)
__global__ __launch_bounds__(1024) void finalize_kernel(
    const float* __restrict__ colH, const float* __restrict__ colW,
    float* __restrict__ De, float* __restrict__ We)
{
  const int b = blockIdx.x;
  const int t = threadIdx.x;
  float cw[2];
  float sq = 0.0f;
  #pragma unroll
  for (int j = 0; j < 2; j++) {
    int i = t + 1024*j;
    float ch = colH[b * NUM + i];
    De[b * NUM + i] = 1.0f / (ch + 1e-10f);
    cw[j] = colW[b * NUM + i];
    sq += cw[j] * cw[j];
  }
  for (int off = 32; off > 0; off >>= 1) sq += __shfl_down(sq, off, 64);
  __shared__ float red[16];
  __shared__ float s_nrm;
  if ((t & 63) == 0) red[t >> 6] = sq;
  __syncthreads();
  if (t == 0) {
    float tot = 0.0f;
    for (int i2 = 0; i2 < 16; i2++) tot += red[i2];
    s_nrm = fmaxf(sqrtf(tot), 1e-12f);
  }
  __syncthreads();
  #pragma unroll
  for (int j = 0; j < 2; j++)
    We[b * NUM + t + 1024*j] = cw[j] / s_nrm;
}

extern "C" void kernel_launch(void* const* d_in, const int* in_sizes, int n_in,
                              void* d_out, int out_size, void* d_ws, size_t ws_size,
                              hipStream_t stream) {
  const float* H0 = (const float*)d_in[0];
  const float* vf = (const float*)d_in[1];
  const float* ef = (const float*)d_in[2];
  const float* Wq = (const float*)d_in[3];
  const float* bq = (const float*)d_in[4];
  const float* Wk = (const float*)d_in[5];
  const float* bk = (const float*)d_in[6];
  const int* iter = (const int*)d_in[7];

  float* out = (float*)d_out;
  const size_t nH = (size_t)2 * NUM * NUM;
  float* Hout  = out;                 // (2,2048,2048)
  float* Wout  = out + nH;            // (2,2048,2048) — holds score temporarily
  float* DeOut = out + 2 * nH;        // (2,2048,1)
  float* DvOut = DeOut + 2 * NUM;     // (2,2048,1)
  float* WeOut = DvOut + 2 * NUM;     // (2,2048,1)

  float* colH = (float*)d_ws;         // 4096 floats
  float* colW = colH + 2 * NUM;       // 4096 floats

  // bf16 Q/K components (6 x 2MB = 12 MB) live in the H region until topk_apply
  const size_t nC = (size_t)2 * NUM * CDIM;
  unsigned short* base = (unsigned short*)Hout;
  unsigned short* Qhi = base;
  unsigned short* Qmd = base + nC;
  unsigned short* Qlo = base + 2 * nC;
  unsigned short* Khi = base + 3 * nC;
  unsigned short* Kmd = base + 4 * nC;
  unsigned short* Klo = base + 5 * nC;

  hipMemsetAsync(d_ws, 0, (size_t)2 * 2 * NUM * sizeof(float), stream);

  proj_kernel<<<dim3(NUM/64, CDIM/64, 4), 256, 0, stream>>>(
      Wq, bq, Wk, bk, vf, ef, Qhi, Qmd, Qlo, Khi, Kmd, Klo);
  score_kernel<<<dim3(NUM/128, NUM/128, 2), 512, 0, stream>>>(
      Qhi, Qmd, Qlo, Khi, Kmd, Klo, H0, Wout);
  topk_apply_kernel<<<dim3(NUM/2), 256, 0, stream>>>(Wout, Hout, iter, DvOut);
  colsum_kernel<<<dim3(NUM/256, NUM/64, 2), 256, 0, stream>>>(Wout, colH, colW);
  finalize_kernel<<<dim3(2), 1024, 0, stream>>>(colH, colW, DeOut, WeOut);
}